// Round 1
// baseline (269.815 us; speedup 1.0000x reference)
//
#include <hip/hip_runtime.h>
#include <math.h>

// Problem constants (N=2, C=256, H=W=64, G=8, P=9, CG=32, K=3, PAD=1)
#define CC    256
#define HH    64
#define WW    64
#define HWSZ  4096
#define NPIX  8192      // N*H*W
#define GG    8
#define PP    9
#define PIX   8         // pixels per block in GEMM kernels
#define CP    260       // padded LDS stride (bank-conflict mitigation)

__device__ __forceinline__ float silu_f(float x) { return x / (1.f + __expf(-x)); }

// ---------------------------------------------------------------------------
// 1) transpose conv1_w (O,C) -> (C,O) so GEMM threads (o) read coalesced
__global__ void k_transpose_w(const float* __restrict__ w, float* __restrict__ wT) {
    int o = blockIdx.x, c = threadIdx.x;
    wT[c * CC + o] = w[o * CC + c];
}

// ---------------------------------------------------------------------------
// 2) 1x1 conv (NCHW input) + BN1(eps=1e-3) + SiLU -> y in NHWC
__global__ void k_conv1(const float* __restrict__ x, const float* __restrict__ wT,
                        const float* __restrict__ g, const float* __restrict__ b,
                        const float* __restrict__ m, const float* __restrict__ v,
                        float* __restrict__ y) {
    __shared__ float xs[PIX * CP];
    int tid = threadIdx.x;
    int pix0 = blockIdx.x * PIX;
    int n = pix0 >> 12;
    int hw0 = pix0 & (HWSZ - 1);
    const float* xn = x + (size_t)n * CC * HWSZ;
    // load 8x256 input tile; group loads 8-contiguous along hw
    for (int rep = 0; rep < PIX; ++rep) {
        int idx = rep * 256 + tid;
        int c = idx >> 3, i = idx & 7;
        xs[i * CP + c] = xn[c * HWSZ + hw0 + i];
    }
    __syncthreads();
    int o = tid;
    float acc[PIX];
#pragma unroll
    for (int i = 0; i < PIX; ++i) acc[i] = 0.f;
    for (int c = 0; c < CC; ++c) {
        float wv = wT[c * CC + o];
#pragma unroll
        for (int i = 0; i < PIX; ++i) acc[i] += xs[i * CP + c] * wv;
    }
    float sc = g[o] * rsqrtf(v[o] + 1e-3f);
    float sh = b[o] - m[o] * sc;
#pragma unroll
    for (int i = 0; i < PIX; ++i) {
        float r = acc[i] * sc + sh;
        y[(size_t)(pix0 + i) * CC + o] = silu_f(r);
    }
}

// ---------------------------------------------------------------------------
// 3) input_proj: xproj = y @ W + b   (NHWC rows)
__global__ void k_inproj(const float* __restrict__ y, const float* __restrict__ w,
                         const float* __restrict__ bias, float* __restrict__ xp) {
    __shared__ float ys[PIX * CP];
    int tid = threadIdx.x;
    int pix0 = blockIdx.x * PIX;
    for (int i = 0; i < PIX; ++i) ys[i * CP + tid] = y[(size_t)(pix0 + i) * CC + tid];
    __syncthreads();
    float acc[PIX];
#pragma unroll
    for (int i = 0; i < PIX; ++i) acc[i] = 0.f;
    for (int c = 0; c < CC; ++c) {
        float wv = w[c * CC + tid];
#pragma unroll
        for (int i = 0; i < PIX; ++i) acc[i] += ys[i * CP + c] * wv;
    }
    float bo = bias[tid];
#pragma unroll
    for (int i = 0; i < PIX; ++i) xp[(size_t)(pix0 + i) * CC + tid] = acc[i] + bo;
}

// ---------------------------------------------------------------------------
// 4) depthwise 3x3 (pad 1) + bias + LayerNorm(C, eps=1e-5) + exact GELU -> z
__global__ void k_dwln(const float* __restrict__ y, const float* __restrict__ dww,
                       const float* __restrict__ dwb, const float* __restrict__ lng,
                       const float* __restrict__ lnb, float* __restrict__ z) {
    int pix = blockIdx.x;
    int c = threadIdx.x;
    int n = pix >> 12, hw = pix & (HWSZ - 1);
    int h = hw >> 6, w = hw & 63;
    float acc = dwb[c];
#pragma unroll
    for (int ky = 0; ky < 3; ++ky) {
        int yy = h + ky - 1;
        if (yy < 0 || yy >= HH) continue;
#pragma unroll
        for (int kx = 0; kx < 3; ++kx) {
            int xx = w + kx - 1;
            if (xx < 0 || xx >= WW) continue;
            acc += y[(size_t)((n << 12) + (yy << 6) + xx) * CC + c] * dww[c * 9 + ky * 3 + kx];
        }
    }
    __shared__ float red[256];
    red[c] = acc;
    __syncthreads();
    for (int s = 128; s > 0; s >>= 1) {
        if (c < s) red[c] += red[c + s];
        __syncthreads();
    }
    float mu = red[0] * (1.f / 256.f);
    __syncthreads();
    red[c] = acc * acc;
    __syncthreads();
    for (int s = 128; s > 0; s >>= 1) {
        if (c < s) red[c] += red[c + s];
        __syncthreads();
    }
    float var = red[0] * (1.f / 256.f) - mu * mu;
    float zn = (acc - mu) * rsqrtf(var + 1e-5f) * lng[c] + lnb[c];
    float ge = 0.5f * zn * (1.f + erff(zn * 0.70710678118654752f));
    z[(size_t)pix * CC + c] = ge;
}

// ---------------------------------------------------------------------------
// 5) offset head (256->144) + mask head (256->72) + softmax over P per group
__global__ void k_heads(const float* __restrict__ z, const float* __restrict__ offw,
                        const float* __restrict__ offb, const float* __restrict__ mw,
                        const float* __restrict__ mb, float* __restrict__ off_out,
                        float* __restrict__ mask_out) {
    __shared__ float zs[PIX * CP];
    __shared__ float ml[PIX][GG * PP];
    int tid = threadIdx.x;
    int pix0 = blockIdx.x * PIX;
    for (int i = 0; i < PIX; ++i) zs[i * CP + tid] = z[(size_t)(pix0 + i) * CC + tid];
    __syncthreads();
    if (tid < 144) {
        float acc[PIX];
#pragma unroll
        for (int i = 0; i < PIX; ++i) acc[i] = 0.f;
        for (int c = 0; c < CC; ++c) {
            float wv = offw[c * 144 + tid];
#pragma unroll
            for (int i = 0; i < PIX; ++i) acc[i] += zs[i * CP + c] * wv;
        }
        float bo = offb[tid];
#pragma unroll
        for (int i = 0; i < PIX; ++i) off_out[(size_t)(pix0 + i) * 144 + tid] = acc[i] + bo;
    } else if (tid < 216) {
        int j = tid - 144;
        float acc[PIX];
#pragma unroll
        for (int i = 0; i < PIX; ++i) acc[i] = 0.f;
        for (int c = 0; c < CC; ++c) {
            float wv = mw[c * 72 + j];
#pragma unroll
            for (int i = 0; i < PIX; ++i) acc[i] += zs[i * CP + c] * wv;
        }
        float bo = mb[j];
#pragma unroll
        for (int i = 0; i < PIX; ++i) ml[i][j] = acc[i] + bo;
    }
    __syncthreads();
    if (tid < 64) {
        int i = tid >> 3, g = tid & 7;
        float mx = -1e30f;
#pragma unroll
        for (int p = 0; p < PP; ++p) mx = fmaxf(mx, ml[i][g * PP + p]);
        float e[PP];
        float s = 0.f;
#pragma unroll
        for (int p = 0; p < PP; ++p) { e[p] = __expf(ml[i][g * PP + p] - mx); s += e[p]; }
        float inv = 1.f / s;
#pragma unroll
        for (int p = 0; p < PP; ++p) mask_out[(size_t)(pix0 + i) * 72 + g * PP + p] = e[p] * inv;
    }
}

// ---------------------------------------------------------------------------
// 6) DCN core: bilinear sample xproj (zero-padded border) weighted by mask
__global__ void k_dcn(const float* __restrict__ xp, const float* __restrict__ off,
                      const float* __restrict__ msk, float* __restrict__ sout) {
    __shared__ float loff[144];
    __shared__ float lm[72];
    int tid = threadIdx.x;
    int pix = blockIdx.x;
    int n = pix >> 12, hw = pix & (HWSZ - 1);
    int h = hw >> 6, w = hw & 63;
    if (tid < 144) loff[tid] = off[(size_t)pix * 144 + tid];
    else if (tid < 216) lm[tid - 144] = msk[(size_t)pix * 72 + (tid - 144)];
    __syncthreads();
    int g = tid >> 5;
    int c = tid;  // g*32+cg == tid
    const float* xpn = xp + (size_t)n * HWSZ * CC;
    float acc = 0.f;
#pragma unroll
    for (int p = 0; p < PP; ++p) {
        float ox = loff[(g * PP + p) * 2];
        float oy = loff[(g * PP + p) * 2 + 1];
        // padded-space sampling coordinate: px = w + p/3 + ox ; py = h + p%3 + oy
        float px = (float)(w + p / 3) + ox;
        float py = (float)(h + p % 3) + oy;
        float fx = floorf(px), fy = floorf(py);
        float wx = px - fx, wy = py - fy;
        int x0 = (int)fx, y0 = (int)fy;
        float mval = lm[g * PP + p];

        float s00 = 0.f, s10 = 0.f, s01 = 0.f, s11 = 0.f;
        int x1 = x0 + 1, y1 = y0 + 1;
        // corner in interior iff 1<=xi<=64 && 1<=yi<=64 -> xproj[yi-1][xi-1]
        if (x0 >= 1 && x0 <= WW && y0 >= 1 && y0 <= HH)
            s00 = xpn[(size_t)(((y0 - 1) << 6) + (x0 - 1)) * CC + c];
        if (x1 >= 1 && x1 <= WW && y0 >= 1 && y0 <= HH)
            s10 = xpn[(size_t)(((y0 - 1) << 6) + (x1 - 1)) * CC + c];
        if (x0 >= 1 && x0 <= WW && y1 >= 1 && y1 <= HH)
            s01 = xpn[(size_t)(((y1 - 1) << 6) + (x0 - 1)) * CC + c];
        if (x1 >= 1 && x1 <= WW && y1 >= 1 && y1 <= HH)
            s11 = xpn[(size_t)(((y1 - 1) << 6) + (x1 - 1)) * CC + c];

        float bil = (1.f - wx) * (1.f - wy) * s00 + wx * (1.f - wy) * s10 +
                    (1.f - wx) * wy * s01 + wx * wy * s11;
        acc += mval * bil;
    }
    sout[(size_t)pix * CC + c] = acc;
}

// ---------------------------------------------------------------------------
// 7) output_proj + BN2(eps=1e-5) + SiLU -> NCHW output
__global__ void k_outproj(const float* __restrict__ s, const float* __restrict__ w,
                          const float* __restrict__ bias, const float* __restrict__ g2,
                          const float* __restrict__ b2, const float* __restrict__ m2,
                          const float* __restrict__ v2, float* __restrict__ out) {
    __shared__ float ss[PIX * CP];
    int tid = threadIdx.x;
    int pix0 = blockIdx.x * PIX;
    int n = pix0 >> 12;
    int hw0 = pix0 & (HWSZ - 1);
    for (int i = 0; i < PIX; ++i) ss[i * CP + tid] = s[(size_t)(pix0 + i) * CC + tid];
    __syncthreads();
    float acc[PIX];
#pragma unroll
    for (int i = 0; i < PIX; ++i) acc[i] = 0.f;
    for (int c = 0; c < CC; ++c) {
        float wv = w[c * CC + tid];
#pragma unroll
        for (int i = 0; i < PIX; ++i) acc[i] += ss[i * CP + c] * wv;
    }
    float sc = g2[tid] * rsqrtf(v2[tid] + 1e-5f);
    float sh = b2[tid] - m2[tid] * sc;
    float bo = bias[tid];
    __syncthreads();
#pragma unroll
    for (int i = 0; i < PIX; ++i) ss[i * CP + tid] = silu_f((acc[i] + bo) * sc + sh);
    __syncthreads();
    float* on = out + (size_t)n * CC * HWSZ;
    for (int rep = 0; rep < PIX; ++rep) {
        int idx = rep * 256 + tid;
        int o = idx >> 3, i = idx & 7;
        on[o * HWSZ + hw0 + i] = ss[i * CP + o];
    }
}

// ---------------------------------------------------------------------------
extern "C" void kernel_launch(void* const* d_in, const int* in_sizes, int n_in,
                              void* d_out, int out_size, void* d_ws, size_t ws_size,
                              hipStream_t stream) {
    const float* x        = (const float*)d_in[0];
    const float* conv1_w  = (const float*)d_in[1];
    const float* bn1_g    = (const float*)d_in[2];
    const float* bn1_b    = (const float*)d_in[3];
    const float* bn1_m    = (const float*)d_in[4];
    const float* bn1_v    = (const float*)d_in[5];
    const float* inproj_w = (const float*)d_in[6];
    const float* inproj_b = (const float*)d_in[7];
    const float* dw_w     = (const float*)d_in[8];
    const float* dw_b     = (const float*)d_in[9];
    const float* ln_g     = (const float*)d_in[10];
    const float* ln_b     = (const float*)d_in[11];
    const float* off_w    = (const float*)d_in[12];
    const float* off_b    = (const float*)d_in[13];
    const float* mask_w   = (const float*)d_in[14];
    const float* mask_b   = (const float*)d_in[15];
    const float* outproj_w = (const float*)d_in[16];
    const float* outproj_b = (const float*)d_in[17];
    const float* bn2_g    = (const float*)d_in[18];
    const float* bn2_b    = (const float*)d_in[19];
    const float* bn2_m    = (const float*)d_in[20];
    const float* bn2_v    = (const float*)d_in[21];
    float* out = (float*)d_out;

    // workspace layout (floats)
    float* ws   = (float*)d_ws;
    float* wT   = ws;                     // 65536
    float* y    = wT + 65536;             // 2097152  (NHWC)
    float* xp   = y + 2097152;            // 2097152
    float* z    = xp + 2097152;           // 2097152
    float* offs = z + 2097152;            // 1179648
    float* msk  = offs + 1179648;         // 589824
    float* sbuf = z;                      // reuse: z dead after k_heads

    k_transpose_w<<<dim3(CC), dim3(CC), 0, stream>>>(conv1_w, wT);
    k_conv1<<<dim3(NPIX / PIX), dim3(256), 0, stream>>>(x, wT, bn1_g, bn1_b, bn1_m, bn1_v, y);
    k_inproj<<<dim3(NPIX / PIX), dim3(256), 0, stream>>>(y, inproj_w, inproj_b, xp);
    k_dwln<<<dim3(NPIX), dim3(256), 0, stream>>>(y, dw_w, dw_b, ln_g, ln_b, z);
    k_heads<<<dim3(NPIX / PIX), dim3(256), 0, stream>>>(z, off_w, off_b, mask_w, mask_b, offs, msk);
    k_dcn<<<dim3(NPIX), dim3(256), 0, stream>>>(xp, offs, msk, sbuf);
    k_outproj<<<dim3(NPIX / PIX), dim3(256), 0, stream>>>(sbuf, outproj_w, outproj_b,
                                                          bn2_g, bn2_b, bn2_m, bn2_v, out);
}

// Round 3
// 255.368 us; speedup vs baseline: 1.0566x; 1.0566x over previous
//
#include <hip/hip_runtime.h>
#include <math.h>

// Problem constants (N=2, C=256, H=W=64, G=8, P=9, CG=32)
#define CC    256
#define HH    64
#define WW    64
#define HWSZ  4096
#define NPIX  8192
#define TP    16        // pixels per GEMM block tile
#define CPAD  260       // LDS row stride (floats), 16B-aligned, conflict-light

__device__ __forceinline__ float silu_f(float x) { return x / (1.f + __expf(-x)); }

// ---------------------------------------------------------------------------
// prep: wT = conv1_w^T (C,O); Wh = [off_w | mask_w | 0] (C,256); bh = [off_b|mask_b|0]
__global__ void k_prep(const float* __restrict__ cw, const float* __restrict__ offw,
                       const float* __restrict__ maskw, const float* __restrict__ offb,
                       const float* __restrict__ maskb,
                       float* __restrict__ wT, float* __restrict__ Wh, float* __restrict__ bh) {
    int c = blockIdx.x, j = threadIdx.x;
    wT[c * CC + j] = cw[j * CC + c];
    float wv = 0.f;
    if (j < 144) wv = offw[c * 144 + j];
    else if (j < 216) wv = maskw[c * 72 + (j - 144)];
    Wh[c * CC + j] = wv;
    if (c == 0) {
        float bv = 0.f;
        if (j < 144) bv = offb[j];
        else if (j < 216) bv = maskb[j - 144];
        bh[j] = bv;
    }
}

// ---------------------------------------------------------------------------
// shared register-tiled GEMM: 16 pixels x 256 outputs per block, 256 threads.
// thread: 4 outputs (ot4..ot4+3) x 4 pixels (pr..pr+3). Weights row-major [c][o].
__device__ __forceinline__ void gemm16(const float* __restrict__ w, const float* xs,
                                       int ot4, int pr, float4 acc[4]) {
    for (int c = 0; c < CC; c += 4) {
        float4 w0 = *(const float4*)(w + (size_t)(c + 0) * CC + ot4);
        float4 w1 = *(const float4*)(w + (size_t)(c + 1) * CC + ot4);
        float4 w2 = *(const float4*)(w + (size_t)(c + 2) * CC + ot4);
        float4 w3 = *(const float4*)(w + (size_t)(c + 3) * CC + ot4);
#pragma unroll
        for (int j = 0; j < 4; ++j) {
            float4 xv = *(const float4*)(xs + (pr + j) * CPAD + c);
            acc[j].x += xv.x * w0.x + xv.y * w1.x + xv.z * w2.x + xv.w * w3.x;
            acc[j].y += xv.x * w0.y + xv.y * w1.y + xv.z * w2.y + xv.w * w3.y;
            acc[j].z += xv.x * w0.z + xv.y * w1.z + xv.z * w2.z + xv.w * w3.z;
            acc[j].w += xv.x * w0.w + xv.y * w1.w + xv.z * w2.w + xv.w * w3.w;
        }
    }
}

// ---------------------------------------------------------------------------
// 1x1 conv (NCHW x) + BN1 + SiLU -> y (NHWC), then fused inproj GEMM -> xp
__global__ __launch_bounds__(256, 2) void k_conv_in(
        const float* __restrict__ x, const float* __restrict__ wT,
        const float* __restrict__ g, const float* __restrict__ b,
        const float* __restrict__ m, const float* __restrict__ v,
        const float* __restrict__ w2, const float* __restrict__ b2,
        float* __restrict__ y, float* __restrict__ xp) {
    __shared__ float xs[TP * CPAD];
    int tid = threadIdx.x;
    int pix0 = blockIdx.x * TP;
    int n = pix0 >> 12, hw0 = pix0 & (HWSZ - 1);
    const float* xn = x + (size_t)n * CC * HWSZ;
    // stage 16x256 x-tile (transpose NCHW -> [pix][c])
    {
        int cbase = tid >> 2;
        int i4 = (tid & 3) * 4;
        for (int rep = 0; rep < 4; ++rep) {
            int c = cbase + rep * 64;
            float4 xv = *(const float4*)(xn + (size_t)c * HWSZ + hw0 + i4);
            xs[(i4 + 0) * CPAD + c] = xv.x;
            xs[(i4 + 1) * CPAD + c] = xv.y;
            xs[(i4 + 2) * CPAD + c] = xv.z;
            xs[(i4 + 3) * CPAD + c] = xv.w;
        }
    }
    __syncthreads();
    int ot4 = (tid & 63) * 4;
    int pr = (tid >> 6) * 4;
    float4 acc[4];
#pragma unroll
    for (int j = 0; j < 4; ++j) acc[j] = make_float4(0.f, 0.f, 0.f, 0.f);
    gemm16(wT, xs, ot4, pr, acc);
    // BN1(eps=1e-3) + SiLU
    float4 gv = *(const float4*)(g + ot4);
    float4 vv = *(const float4*)(v + ot4);
    float4 mv = *(const float4*)(m + ot4);
    float4 bv = *(const float4*)(b + ot4);
    float4 sc, sh;
    sc.x = gv.x * rsqrtf(vv.x + 1e-3f); sh.x = bv.x - mv.x * sc.x;
    sc.y = gv.y * rsqrtf(vv.y + 1e-3f); sh.y = bv.y - mv.y * sc.y;
    sc.z = gv.z * rsqrtf(vv.z + 1e-3f); sh.z = bv.z - mv.z * sc.z;
    sc.w = gv.w * rsqrtf(vv.w + 1e-3f); sh.w = bv.w - mv.w * sc.w;
    float4 yv[4];
#pragma unroll
    for (int j = 0; j < 4; ++j) {
        yv[j].x = silu_f(acc[j].x * sc.x + sh.x);
        yv[j].y = silu_f(acc[j].y * sc.y + sh.y);
        yv[j].z = silu_f(acc[j].z * sc.z + sh.z);
        yv[j].w = silu_f(acc[j].w * sc.w + sh.w);
        *(float4*)(y + (size_t)(pix0 + pr + j) * CC + ot4) = yv[j];
    }
    __syncthreads();   // all gemm16 reads of xs done
#pragma unroll
    for (int j = 0; j < 4; ++j)
        *(float4*)(&xs[(pr + j) * CPAD + ot4]) = yv[j];
    __syncthreads();
    // inproj GEMM
#pragma unroll
    for (int j = 0; j < 4; ++j) acc[j] = make_float4(0.f, 0.f, 0.f, 0.f);
    gemm16(w2, xs, ot4, pr, acc);
    float4 bb = *(const float4*)(b2 + ot4);
#pragma unroll
    for (int j = 0; j < 4; ++j) {
        acc[j].x += bb.x; acc[j].y += bb.y; acc[j].z += bb.z; acc[j].w += bb.w;
        *(float4*)(xp + (size_t)(pix0 + pr + j) * CC + ot4) = acc[j];
    }
}

// ---------------------------------------------------------------------------
// depthwise 3x3 + bias + LayerNorm + exact GELU. One wave per pixel.
__global__ __launch_bounds__(256, 2) void k_dwln(
        const float* __restrict__ y, const float* __restrict__ dww,
        const float* __restrict__ dwb, const float* __restrict__ lng,
        const float* __restrict__ lnb, float* __restrict__ z) {
    int tid = threadIdx.x;
    int wv = tid >> 6, l = tid & 63;
    int pix = blockIdx.x * 4 + wv;
    int n = pix >> 12, hw = pix & (HWSZ - 1);
    int h = hw >> 6, wx_ = hw & 63;
    int c0 = l * 4;
    float wloc[36];
    const float4* wp = (const float4*)(dww + c0 * 9);
#pragma unroll
    for (int k = 0; k < 9; ++k) ((float4*)wloc)[k] = wp[k];
    float4 acc = *(const float4*)(dwb + c0);
    const float* yn = y + (size_t)n * HWSZ * CC;
#pragma unroll
    for (int ky = 0; ky < 3; ++ky) {
        int yy = h + ky - 1;
        if (yy < 0 || yy >= HH) continue;
#pragma unroll
        for (int kx = 0; kx < 3; ++kx) {
            int xx = wx_ + kx - 1;
            if (xx < 0 || xx >= WW) continue;
            float4 yv = *(const float4*)(yn + (size_t)((yy << 6) + xx) * CC + c0);
            int t = ky * 3 + kx;
            acc.x += yv.x * wloc[0 * 9 + t];
            acc.y += yv.y * wloc[1 * 9 + t];
            acc.z += yv.z * wloc[2 * 9 + t];
            acc.w += yv.w * wloc[3 * 9 + t];
        }
    }
    float s1 = acc.x + acc.y + acc.z + acc.w;
    float s2 = acc.x * acc.x + acc.y * acc.y + acc.z * acc.z + acc.w * acc.w;
#pragma unroll
    for (int off = 32; off > 0; off >>= 1) {
        s1 += __shfl_xor(s1, off);
        s2 += __shfl_xor(s2, off);
    }
    float mu = s1 * (1.f / 256.f);
    float var = s2 * (1.f / 256.f) - mu * mu;
    float rs = rsqrtf(var + 1e-5f);
    float4 gv = *(const float4*)(lng + c0);
    float4 bv = *(const float4*)(lnb + c0);
    float4 zv;
    zv.x = (acc.x - mu) * rs * gv.x + bv.x;
    zv.y = (acc.y - mu) * rs * gv.y + bv.y;
    zv.z = (acc.z - mu) * rs * gv.z + bv.z;
    zv.w = (acc.w - mu) * rs * gv.w + bv.w;
    zv.x = 0.5f * zv.x * (1.f + erff(zv.x * 0.70710678118654752f));
    zv.y = 0.5f * zv.y * (1.f + erff(zv.y * 0.70710678118654752f));
    zv.z = 0.5f * zv.z * (1.f + erff(zv.z * 0.70710678118654752f));
    zv.w = 0.5f * zv.w * (1.f + erff(zv.w * 0.70710678118654752f));
    *(float4*)(z + (size_t)pix * CC + c0) = zv;
}

// ---------------------------------------------------------------------------
// heads: combined [offset|mask] GEMM (uniform waves) + per-group softmax
__global__ __launch_bounds__(256, 2) void k_heads(
        const float* __restrict__ z, const float* __restrict__ Wh,
        const float* __restrict__ bh, float* __restrict__ offs,
        float* __restrict__ msk) {
    __shared__ float xs[TP * CPAD];
    __shared__ float ml[TP][72];
    int tid = threadIdx.x;
    int pix0 = blockIdx.x * TP;
    for (int k = 0; k < 4; ++k) {
        int f = tid + k * 256;
        int pi = f >> 6, c4 = (f & 63) * 4;
        float4 zv = *(const float4*)(z + (size_t)(pix0 + pi) * CC + c4);
        *(float4*)(&xs[pi * CPAD + c4]) = zv;
    }
    __syncthreads();
    int ot = tid & 63;
    int ot4 = ot * 4;
    int pr = (tid >> 6) * 4;
    float4 acc[4];
#pragma unroll
    for (int j = 0; j < 4; ++j) acc[j] = make_float4(0.f, 0.f, 0.f, 0.f);
    gemm16(Wh, xs, ot4, pr, acc);
    float4 bb = *(const float4*)(bh + ot4);
#pragma unroll
    for (int j = 0; j < 4; ++j) {
        acc[j].x += bb.x; acc[j].y += bb.y; acc[j].z += bb.z; acc[j].w += bb.w;
    }
    if (ot < 36) {
#pragma unroll
        for (int j = 0; j < 4; ++j)
            *(float4*)(offs + (size_t)(pix0 + pr + j) * 144 + ot4) = acc[j];
    } else if (ot < 54) {
        int mo = ot4 - 144;
#pragma unroll
        for (int j = 0; j < 4; ++j)
            *(float4*)(&ml[pr + j][mo]) = acc[j];
    }
    __syncthreads();
    if (tid < 128) {
        int pi = tid >> 3, g = tid & 7;
        float mx = -1e30f;
#pragma unroll
        for (int p = 0; p < 9; ++p) mx = fmaxf(mx, ml[pi][g * 9 + p]);
        float e[9], s = 0.f;
#pragma unroll
        for (int p = 0; p < 9; ++p) { e[p] = __expf(ml[pi][g * 9 + p] - mx); s += e[p]; }
        float inv = 1.f / s;
        float* mp = msk + (size_t)(pix0 + pi) * 72 + g * 9;
#pragma unroll
        for (int p = 0; p < 9; ++p) mp[p] = e[p] * inv;
    }
}

// ---------------------------------------------------------------------------
// DCN core: float4 over 4 channels, one wave per pixel
__global__ __launch_bounds__(256, 2) void k_dcn(
        const float* __restrict__ xp, const float* __restrict__ offs,
        const float* __restrict__ msk, float* __restrict__ sout) {
    __shared__ float loff[4][144];
    __shared__ float lm[4][72];
    int tid = threadIdx.x;
    int wv = tid >> 6, l = tid & 63;
    int pix = blockIdx.x * 4 + wv;
    const float* op = offs + (size_t)pix * 144;
    const float* mp = msk + (size_t)pix * 72;
    // 144 offsets with 64 lanes: three passes (FIX: previous version missed 128..143)
    loff[wv][l] = op[l];
    loff[wv][64 + l] = op[64 + l];
    if (l < 16) loff[wv][128 + l] = op[128 + l];
    lm[wv][l] = mp[l];
    if (l < 8) lm[wv][64 + l] = mp[64 + l];
    __syncthreads();
    int n = pix >> 12, hw = pix & (HWSZ - 1);
    int h = hw >> 6, w = hw & 63;
    int g = l >> 3, q = l & 7;
    int c0 = g * 32 + q * 4;
    const float* xpn = xp + (size_t)n * HWSZ * CC;
    float4 acc = make_float4(0.f, 0.f, 0.f, 0.f);
#pragma unroll
    for (int p = 0; p < 9; ++p) {
        float ox = loff[wv][(g * 9 + p) * 2];
        float oy = loff[wv][(g * 9 + p) * 2 + 1];
        float px = (float)(w + p / 3) + ox;
        float py = (float)(h + p % 3) + oy;
        float fx = floorf(px), fy = floorf(py);
        float wx1 = px - fx, wy1 = py - fy;
        int x0 = (int)fx, y0 = (int)fy;
        int x1 = x0 + 1, y1 = y0 + 1;
        float mval = lm[wv][g * 9 + p];
        float w00 = (1.f - wx1) * (1.f - wy1) * mval;
        float w10 = wx1 * (1.f - wy1) * mval;
        float w01 = (1.f - wx1) * wy1 * mval;
        float w11 = wx1 * wy1 * mval;
        if (x0 >= 1 && x0 <= WW && y0 >= 1 && y0 <= HH) {
            float4 s = *(const float4*)(xpn + (size_t)(((y0 - 1) << 6) + (x0 - 1)) * CC + c0);
            acc.x += w00 * s.x; acc.y += w00 * s.y; acc.z += w00 * s.z; acc.w += w00 * s.w;
        }
        if (x1 >= 1 && x1 <= WW && y0 >= 1 && y0 <= HH) {
            float4 s = *(const float4*)(xpn + (size_t)(((y0 - 1) << 6) + (x1 - 1)) * CC + c0);
            acc.x += w10 * s.x; acc.y += w10 * s.y; acc.z += w10 * s.z; acc.w += w10 * s.w;
        }
        if (x0 >= 1 && x0 <= WW && y1 >= 1 && y1 <= HH) {
            float4 s = *(const float4*)(xpn + (size_t)(((y1 - 1) << 6) + (x0 - 1)) * CC + c0);
            acc.x += w01 * s.x; acc.y += w01 * s.y; acc.z += w01 * s.z; acc.w += w01 * s.w;
        }
        if (x1 >= 1 && x1 <= WW && y1 >= 1 && y1 <= HH) {
            float4 s = *(const float4*)(xpn + (size_t)(((y1 - 1) << 6) + (x1 - 1)) * CC + c0);
            acc.x += w11 * s.x; acc.y += w11 * s.y; acc.z += w11 * s.z; acc.w += w11 * s.w;
        }
    }
    *(float4*)(sout + (size_t)pix * CC + c0) = acc;
}

// ---------------------------------------------------------------------------
// outproj GEMM + bias + BN2 + SiLU -> NCHW out (LDS transpose)
__global__ __launch_bounds__(256, 2) void k_out(
        const float* __restrict__ s, const float* __restrict__ w,
        const float* __restrict__ bias, const float* __restrict__ g2,
        const float* __restrict__ b2, const float* __restrict__ m2,
        const float* __restrict__ v2, float* __restrict__ out) {
    __shared__ float xs[TP * CPAD];
    int tid = threadIdx.x;
    int pix0 = blockIdx.x * TP;
    for (int k = 0; k < 4; ++k) {
        int f = tid + k * 256;
        int pi = f >> 6, c4 = (f & 63) * 4;
        float4 sv = *(const float4*)(s + (size_t)(pix0 + pi) * CC + c4);
        *(float4*)(&xs[pi * CPAD + c4]) = sv;
    }
    __syncthreads();
    int ot4 = (tid & 63) * 4;
    int pr = (tid >> 6) * 4;
    float4 acc[4];
#pragma unroll
    for (int j = 0; j < 4; ++j) acc[j] = make_float4(0.f, 0.f, 0.f, 0.f);
    gemm16(w, xs, ot4, pr, acc);
    float4 bb = *(const float4*)(bias + ot4);
    float4 gv = *(const float4*)(g2 + ot4);
    float4 vv = *(const float4*)(v2 + ot4);
    float4 mv = *(const float4*)(m2 + ot4);
    float4 bv = *(const float4*)(b2 + ot4);
    float4 sc, sh;
    sc.x = gv.x * rsqrtf(vv.x + 1e-5f); sh.x = bv.x - mv.x * sc.x;
    sc.y = gv.y * rsqrtf(vv.y + 1e-5f); sh.y = bv.y - mv.y * sc.y;
    sc.z = gv.z * rsqrtf(vv.z + 1e-5f); sh.z = bv.z - mv.z * sc.z;
    sc.w = gv.w * rsqrtf(vv.w + 1e-5f); sh.w = bv.w - mv.w * sc.w;
    float4 res[4];
#pragma unroll
    for (int j = 0; j < 4; ++j) {
        res[j].x = silu_f((acc[j].x + bb.x) * sc.x + sh.x);
        res[j].y = silu_f((acc[j].y + bb.y) * sc.y + sh.y);
        res[j].z = silu_f((acc[j].z + bb.z) * sc.z + sh.z);
        res[j].w = silu_f((acc[j].w + bb.w) * sc.w + sh.w);
    }
    __syncthreads();
#pragma unroll
    for (int j = 0; j < 4; ++j)
        *(float4*)(&xs[(pr + j) * CPAD + ot4]) = res[j];
    __syncthreads();
    int n = pix0 >> 12, hw0 = pix0 & (HWSZ - 1);
    float* on = out + (size_t)n * CC * HWSZ + (size_t)tid * HWSZ + hw0;
#pragma unroll
    for (int i4 = 0; i4 < TP; i4 += 4) {
        float4 ov;
        ov.x = xs[(i4 + 0) * CPAD + tid];
        ov.y = xs[(i4 + 1) * CPAD + tid];
        ov.z = xs[(i4 + 2) * CPAD + tid];
        ov.w = xs[(i4 + 3) * CPAD + tid];
        *(float4*)(on + i4) = ov;
    }
}

// ---------------------------------------------------------------------------
extern "C" void kernel_launch(void* const* d_in, const int* in_sizes, int n_in,
                              void* d_out, int out_size, void* d_ws, size_t ws_size,
                              hipStream_t stream) {
    const float* x        = (const float*)d_in[0];
    const float* conv1_w  = (const float*)d_in[1];
    const float* bn1_g    = (const float*)d_in[2];
    const float* bn1_b    = (const float*)d_in[3];
    const float* bn1_m    = (const float*)d_in[4];
    const float* bn1_v    = (const float*)d_in[5];
    const float* inproj_w = (const float*)d_in[6];
    const float* inproj_b = (const float*)d_in[7];
    const float* dw_w     = (const float*)d_in[8];
    const float* dw_b     = (const float*)d_in[9];
    const float* ln_g     = (const float*)d_in[10];
    const float* ln_b     = (const float*)d_in[11];
    const float* off_w    = (const float*)d_in[12];
    const float* off_b    = (const float*)d_in[13];
    const float* mask_w   = (const float*)d_in[14];
    const float* mask_b   = (const float*)d_in[15];
    const float* outproj_w = (const float*)d_in[16];
    const float* outproj_b = (const float*)d_in[17];
    const float* bn2_g    = (const float*)d_in[18];
    const float* bn2_b    = (const float*)d_in[19];
    const float* bn2_m    = (const float*)d_in[20];
    const float* bn2_v    = (const float*)d_in[21];
    float* out = (float*)d_out;

    float* ws   = (float*)d_ws;
    float* wT   = ws;                      // 65536
    float* Wh   = wT + 65536;              // 65536
    float* bh   = Wh + 65536;              // 256
    float* y    = bh + 256;                // 2097152 (NHWC)
    float* xp   = y + 2097152;             // 2097152
    float* z    = xp + 2097152;            // 2097152
    float* offs = z + 2097152;             // 1179648
    float* msk  = offs + 1179648;          // 589824
    float* sbuf = z;                       // z dead after k_heads

    k_prep<<<dim3(CC), dim3(CC), 0, stream>>>(conv1_w, off_w, mask_w, off_b, mask_b, wT, Wh, bh);
    k_conv_in<<<dim3(NPIX / TP), dim3(256), 0, stream>>>(x, wT, bn1_g, bn1_b, bn1_m, bn1_v,
                                                         inproj_w, inproj_b, y, xp);
    k_dwln<<<dim3(NPIX / 4), dim3(256), 0, stream>>>(y, dw_w, dw_b, ln_g, ln_b, z);
    k_heads<<<dim3(NPIX / TP), dim3(256), 0, stream>>>(z, Wh, bh, offs, msk);
    k_dcn<<<dim3(NPIX / 4), dim3(256), 0, stream>>>(xp, offs, msk, sbuf);
    k_out<<<dim3(NPIX / TP), dim3(256), 0, stream>>>(sbuf, outproj_w, outproj_b,
                                                     bn2_g, bn2_b, bn2_m, bn2_v, out);
}

// Round 4
// 177.818 us; speedup vs baseline: 1.5174x; 1.4361x over previous
//
#include <hip/hip_runtime.h>
#include <math.h>

// Problem constants (N=2, C=256, H=W=64, G=8, P=9, CG=32)
#define CC    256
#define HH    64
#define WW    64
#define HWSZ  4096
#define NPIX  8192
#define MT    16        // pixels per GEMM block tile (M)
#define ASTR  264       // A-tile LDS row stride in bf16 elems (528 B: odd mult of 16B -> 2-way max)

typedef __attribute__((ext_vector_type(8))) short short8;
typedef __attribute__((ext_vector_type(4))) float f32x4;

__device__ __forceinline__ float silu_f(float x) { return x / (1.f + __expf(-x)); }

// fp32 -> bf16 with round-to-nearest-even
__device__ __forceinline__ short f2bf(float f) {
    unsigned u = __float_as_uint(f);
    unsigned r = (u + 0x7fffu + ((u >> 16) & 1u)) >> 16;
    return (short)r;
}
__device__ __forceinline__ unsigned pk2(float a, float b) {
    return (unsigned)(unsigned short)f2bf(a) | ((unsigned)(unsigned short)f2bf(b) << 16);
}

// ---------------------------------------------------------------------------
// prep: bf16 weights in (O,C) o-major layout; fused epilogue params.
// Wc1b = conv1_w (already O,C); Wipb = inproj_w^T; Whb = [off|mask|0]^T; Wopb = outproj_w^T
__global__ void k_prep(const float* __restrict__ cw, const float* __restrict__ ipw,
                       const float* __restrict__ offw, const float* __restrict__ maskw,
                       const float* __restrict__ opw,
                       const float* __restrict__ offb, const float* __restrict__ maskb,
                       const float* __restrict__ g1, const float* __restrict__ b1,
                       const float* __restrict__ m1, const float* __restrict__ v1,
                       const float* __restrict__ g2, const float* __restrict__ b2,
                       const float* __restrict__ m2, const float* __restrict__ v2,
                       short* __restrict__ Wc1b, short* __restrict__ Wipb,
                       short* __restrict__ Whb, short* __restrict__ Wopb,
                       float* __restrict__ bh, float* __restrict__ sc1, float* __restrict__ sh1,
                       float* __restrict__ sc2, float* __restrict__ sh2) {
    int o = blockIdx.x, c = threadIdx.x;
    Wc1b[o * CC + c] = f2bf(cw[o * CC + c]);
    Wipb[o * CC + c] = f2bf(ipw[c * CC + o]);
    float hv = 0.f;
    if (o < 144) hv = offw[c * 144 + o];
    else if (o < 216) hv = maskw[c * 72 + (o - 144)];
    Whb[o * CC + c] = f2bf(hv);
    Wopb[o * CC + c] = f2bf(opw[c * CC + o]);
    if (o == 0) {
        float bv = 0.f;
        if (c < 144) bv = offb[c];
        else if (c < 216) bv = maskb[c - 144];
        bh[c] = bv;
        float s1 = g1[c] * rsqrtf(v1[c] + 1e-3f);
        sc1[c] = s1; sh1[c] = b1[c] - m1[c] * s1;
        float s2 = g2[c] * rsqrtf(v2[c] + 1e-5f);
        sc2[c] = s2; sh2[c] = b2[c] - m2[c] * s2;
    }
}

// ---------------------------------------------------------------------------
// stage a contiguous fp32 [16 x 256] tile into LDS bf16 A-tile (rows stride ASTR)
__device__ __forceinline__ void stage_tile(const float* __restrict__ src, short* As, int tid) {
#pragma unroll
    for (int k = 0; k < 4; ++k) {
        int f = tid + k * 256;          // float4 index within tile (1024 total)
        float4 v = ((const float4*)src)[f];
        int pix = f >> 6, c = (f & 63) * 4;
        *(uint2*)(As + pix * ASTR + c) = make_uint2(pk2(v.x, v.y), pk2(v.z, v.w));
    }
}

// ---------------------------------------------------------------------------
// MFMA GEMM: 16 pixels x 256 outputs, K=256. Wave wv covers outputs [wv*64, wv*64+64).
// A from LDS (layout A[m=lane&15][k=quad*8+j]); B direct from global bf16 (O,C) o-major
// (lane reads W[o=n0+nt*16+(lane&15)][c = c0+quad*8 .. +7], 16 contiguous bytes).
__device__ __forceinline__ void mfma_gemm(const short* As, const short* __restrict__ Wb,
                                          int lane, int n0, f32x4 acc[4]) {
    const int m = lane & 15, q = lane >> 4;
#pragma unroll
    for (int kk = 0; kk < 8; ++kk) {
        int c0 = kk * 32 + q * 8;
        short8 a = *(const short8*)(As + m * ASTR + c0);
#pragma unroll
        for (int nt = 0; nt < 4; ++nt) {
            short8 b = *(const short8*)(Wb + (size_t)(n0 + nt * 16 + m) * CC + c0);
            acc[nt] = __builtin_amdgcn_mfma_f32_16x16x32_bf16(a, b, acc[nt], 0, 0, 0);
        }
    }
}

// ---------------------------------------------------------------------------
// conv1(1x1, NCHW) + BN1 + SiLU -> y (NHWC fp32) ; fused inproj -> xp (fp32)
__global__ void k_conv_in(const float* __restrict__ x, const short* __restrict__ Wc1b,
                          const short* __restrict__ Wipb, const float* __restrict__ sc1,
                          const float* __restrict__ sh1, const float* __restrict__ ipb,
                          float* __restrict__ y, float* __restrict__ xp) {
    __shared__ __align__(16) short As[MT * ASTR];
    int tid = threadIdx.x;
    int pix0 = blockIdx.x * MT;
    int n = pix0 >> 12, hw0 = pix0 & (HWSZ - 1);
    const float* xn = x + (size_t)n * CC * HWSZ;
    // stage x-tile (NCHW -> [pix][c] bf16)
    {
        int i4 = (tid & 3) * 4;
#pragma unroll
        for (int rep = 0; rep < 4; ++rep) {
            int c = (tid >> 2) + rep * 64;
            float4 v = *(const float4*)(xn + (size_t)c * HWSZ + hw0 + i4);
            As[(i4 + 0) * ASTR + c] = f2bf(v.x);
            As[(i4 + 1) * ASTR + c] = f2bf(v.y);
            As[(i4 + 2) * ASTR + c] = f2bf(v.z);
            As[(i4 + 3) * ASTR + c] = f2bf(v.w);
        }
    }
    __syncthreads();
    int lane = tid & 63, n0 = (tid >> 6) * 64;
    int col = lane & 15, qr = (lane >> 4) * 4;
    f32x4 acc[4];
#pragma unroll
    for (int nt = 0; nt < 4; ++nt) acc[nt] = (f32x4){0.f, 0.f, 0.f, 0.f};
    mfma_gemm(As, Wc1b, lane, n0, acc);
    __syncthreads();   // all A-reads done before overwrite
#pragma unroll
    for (int nt = 0; nt < 4; ++nt) {
        int o = n0 + nt * 16 + col;
        float sc = sc1[o], sh = sh1[o];
#pragma unroll
        for (int r = 0; r < 4; ++r) {
            int pix = qr + r;
            float val = silu_f(acc[nt][r] * sc + sh);
            y[(size_t)(pix0 + pix) * CC + o] = val;
            As[pix * ASTR + o] = f2bf(val);
        }
    }
    __syncthreads();
#pragma unroll
    for (int nt = 0; nt < 4; ++nt) acc[nt] = (f32x4){0.f, 0.f, 0.f, 0.f};
    mfma_gemm(As, Wipb, lane, n0, acc);
#pragma unroll
    for (int nt = 0; nt < 4; ++nt) {
        int o = n0 + nt * 16 + col;
        float bo = ipb[o];
#pragma unroll
        for (int r = 0; r < 4; ++r)
            xp[(size_t)(pix0 + qr + r) * CC + o] = acc[nt][r] + bo;
    }
}

// ---------------------------------------------------------------------------
// depthwise 3x3 + bias + LayerNorm + exact GELU. One wave per pixel. (unchanged)
__global__ __launch_bounds__(256, 2) void k_dwln(
        const float* __restrict__ y, const float* __restrict__ dww,
        const float* __restrict__ dwb, const float* __restrict__ lng,
        const float* __restrict__ lnb, float* __restrict__ z) {
    int tid = threadIdx.x;
    int wv = tid >> 6, l = tid & 63;
    int pix = blockIdx.x * 4 + wv;
    int n = pix >> 12, hw = pix & (HWSZ - 1);
    int h = hw >> 6, wx_ = hw & 63;
    int c0 = l * 4;
    float wloc[36];
    const float4* wp = (const float4*)(dww + c0 * 9);
#pragma unroll
    for (int k = 0; k < 9; ++k) ((float4*)wloc)[k] = wp[k];
    float4 acc = *(const float4*)(dwb + c0);
    const float* yn = y + (size_t)n * HWSZ * CC;
#pragma unroll
    for (int ky = 0; ky < 3; ++ky) {
        int yy = h + ky - 1;
        if (yy < 0 || yy >= HH) continue;
#pragma unroll
        for (int kx = 0; kx < 3; ++kx) {
            int xx = wx_ + kx - 1;
            if (xx < 0 || xx >= WW) continue;
            float4 yv = *(const float4*)(yn + (size_t)((yy << 6) + xx) * CC + c0);
            int t = ky * 3 + kx;
            acc.x += yv.x * wloc[0 * 9 + t];
            acc.y += yv.y * wloc[1 * 9 + t];
            acc.z += yv.z * wloc[2 * 9 + t];
            acc.w += yv.w * wloc[3 * 9 + t];
        }
    }
    float s1 = acc.x + acc.y + acc.z + acc.w;
    float s2 = acc.x * acc.x + acc.y * acc.y + acc.z * acc.z + acc.w * acc.w;
#pragma unroll
    for (int off = 32; off > 0; off >>= 1) {
        s1 += __shfl_xor(s1, off);
        s2 += __shfl_xor(s2, off);
    }
    float mu = s1 * (1.f / 256.f);
    float var = s2 * (1.f / 256.f) - mu * mu;
    float rs = rsqrtf(var + 1e-5f);
    float4 gv = *(const float4*)(lng + c0);
    float4 bv = *(const float4*)(lnb + c0);
    float4 zv;
    zv.x = (acc.x - mu) * rs * gv.x + bv.x;
    zv.y = (acc.y - mu) * rs * gv.y + bv.y;
    zv.z = (acc.z - mu) * rs * gv.z + bv.z;
    zv.w = (acc.w - mu) * rs * gv.w + bv.w;
    zv.x = 0.5f * zv.x * (1.f + erff(zv.x * 0.70710678118654752f));
    zv.y = 0.5f * zv.y * (1.f + erff(zv.y * 0.70710678118654752f));
    zv.z = 0.5f * zv.z * (1.f + erff(zv.z * 0.70710678118654752f));
    zv.w = 0.5f * zv.w * (1.f + erff(zv.w * 0.70710678118654752f));
    *(float4*)(z + (size_t)pix * CC + c0) = zv;
}

// ---------------------------------------------------------------------------
// heads: combined [offset|mask|pad] MFMA GEMM + per-group softmax
__global__ void k_heads(const float* __restrict__ z, const short* __restrict__ Whb,
                        const float* __restrict__ bh, float* __restrict__ offs,
                        float* __restrict__ msk) {
    __shared__ __align__(16) short As[MT * ASTR];
    __shared__ float ml[MT * 76];
    int tid = threadIdx.x;
    int pix0 = blockIdx.x * MT;
    stage_tile(z + (size_t)pix0 * CC, As, tid);
    __syncthreads();
    int lane = tid & 63, n0 = (tid >> 6) * 64;
    int col = lane & 15, qr = (lane >> 4) * 4;
    f32x4 acc[4];
#pragma unroll
    for (int nt = 0; nt < 4; ++nt) acc[nt] = (f32x4){0.f, 0.f, 0.f, 0.f};
    mfma_gemm(As, Whb, lane, n0, acc);
#pragma unroll
    for (int nt = 0; nt < 4; ++nt) {
        int o = n0 + nt * 16 + col;
        float bo = bh[o];
#pragma unroll
        for (int r = 0; r < 4; ++r) {
            int pix = qr + r;
            float v = acc[nt][r] + bo;
            if (o < 144) offs[(size_t)(pix0 + pix) * 144 + o] = v;
            else if (o < 216) ml[pix * 76 + (o - 144)] = v;
        }
    }
    __syncthreads();
    if (tid < 128) {
        int pi = tid >> 3, g = tid & 7;
        const float* row = ml + pi * 76 + g * 9;
        float mx = -1e30f;
#pragma unroll
        for (int p = 0; p < 9; ++p) mx = fmaxf(mx, row[p]);
        float e[9], s = 0.f;
#pragma unroll
        for (int p = 0; p < 9; ++p) { e[p] = __expf(row[p] - mx); s += e[p]; }
        float inv = 1.f / s;
        float* mp = msk + (size_t)(pix0 + pi) * 72 + g * 9;
#pragma unroll
        for (int p = 0; p < 9; ++p) mp[p] = e[p] * inv;
    }
}

// ---------------------------------------------------------------------------
// DCN core: float4 over 4 channels, one wave per pixel (unchanged)
__global__ __launch_bounds__(256, 2) void k_dcn(
        const float* __restrict__ xp, const float* __restrict__ offs,
        const float* __restrict__ msk, float* __restrict__ sout) {
    __shared__ float loff[4][144];
    __shared__ float lm[4][72];
    int tid = threadIdx.x;
    int wv = tid >> 6, l = tid & 63;
    int pix = blockIdx.x * 4 + wv;
    const float* op = offs + (size_t)pix * 144;
    const float* mp = msk + (size_t)pix * 72;
    loff[wv][l] = op[l];
    loff[wv][64 + l] = op[64 + l];
    if (l < 16) loff[wv][128 + l] = op[128 + l];
    lm[wv][l] = mp[l];
    if (l < 8) lm[wv][64 + l] = mp[64 + l];
    __syncthreads();
    int n = pix >> 12, hw = pix & (HWSZ - 1);
    int h = hw >> 6, w = hw & 63;
    int g = l >> 3, q = l & 7;
    int c0 = g * 32 + q * 4;
    const float* xpn = xp + (size_t)n * HWSZ * CC;
    float4 acc = make_float4(0.f, 0.f, 0.f, 0.f);
#pragma unroll
    for (int p = 0; p < 9; ++p) {
        float ox = loff[wv][(g * 9 + p) * 2];
        float oy = loff[wv][(g * 9 + p) * 2 + 1];
        float px = (float)(w + p / 3) + ox;
        float py = (float)(h + p % 3) + oy;
        float fx = floorf(px), fy = floorf(py);
        float wx1 = px - fx, wy1 = py - fy;
        int x0 = (int)fx, y0 = (int)fy;
        int x1 = x0 + 1, y1 = y0 + 1;
        float mval = lm[wv][g * 9 + p];
        float w00 = (1.f - wx1) * (1.f - wy1) * mval;
        float w10 = wx1 * (1.f - wy1) * mval;
        float w01 = (1.f - wx1) * wy1 * mval;
        float w11 = wx1 * wy1 * mval;
        if (x0 >= 1 && x0 <= WW && y0 >= 1 && y0 <= HH) {
            float4 s = *(const float4*)(xpn + (size_t)(((y0 - 1) << 6) + (x0 - 1)) * CC + c0);
            acc.x += w00 * s.x; acc.y += w00 * s.y; acc.z += w00 * s.z; acc.w += w00 * s.w;
        }
        if (x1 >= 1 && x1 <= WW && y0 >= 1 && y0 <= HH) {
            float4 s = *(const float4*)(xpn + (size_t)(((y0 - 1) << 6) + (x1 - 1)) * CC + c0);
            acc.x += w10 * s.x; acc.y += w10 * s.y; acc.z += w10 * s.z; acc.w += w10 * s.w;
        }
        if (x0 >= 1 && x0 <= WW && y1 >= 1 && y1 <= HH) {
            float4 s = *(const float4*)(xpn + (size_t)(((y1 - 1) << 6) + (x0 - 1)) * CC + c0);
            acc.x += w01 * s.x; acc.y += w01 * s.y; acc.z += w01 * s.z; acc.w += w01 * s.w;
        }
        if (x1 >= 1 && x1 <= WW && y1 >= 1 && y1 <= HH) {
            float4 s = *(const float4*)(xpn + (size_t)(((y1 - 1) << 6) + (x1 - 1)) * CC + c0);
            acc.x += w11 * s.x; acc.y += w11 * s.y; acc.z += w11 * s.z; acc.w += w11 * s.w;
        }
    }
    *(float4*)(sout + (size_t)pix * CC + c0) = acc;
}

// ---------------------------------------------------------------------------
// outproj MFMA GEMM + bias + BN2 + SiLU -> NCHW out (LDS transpose)
__global__ void k_out(const float* __restrict__ s, const short* __restrict__ Wopb,
                      const float* __restrict__ opb, const float* __restrict__ sc2,
                      const float* __restrict__ sh2, float* __restrict__ out) {
    __shared__ __align__(16) short As[MT * ASTR];
    __shared__ float xs[MT * 260];
    int tid = threadIdx.x;
    int pix0 = blockIdx.x * MT;
    stage_tile(s + (size_t)pix0 * CC, As, tid);
    __syncthreads();
    int lane = tid & 63, n0 = (tid >> 6) * 64;
    int col = lane & 15, qr = (lane >> 4) * 4;
    f32x4 acc[4];
#pragma unroll
    for (int nt = 0; nt < 4; ++nt) acc[nt] = (f32x4){0.f, 0.f, 0.f, 0.f};
    mfma_gemm(As, Wopb, lane, n0, acc);
#pragma unroll
    for (int nt = 0; nt < 4; ++nt) {
        int o = n0 + nt * 16 + col;
        float bo = opb[o], sc = sc2[o], sh = sh2[o];
#pragma unroll
        for (int r = 0; r < 4; ++r)
            xs[(qr + r) * 260 + o] = silu_f((acc[nt][r] + bo) * sc + sh);
    }
    __syncthreads();
    int n = pix0 >> 12, hw0 = pix0 & (HWSZ - 1);
    float* on = out + (size_t)n * CC * HWSZ + (size_t)tid * HWSZ + hw0;
#pragma unroll
    for (int i4 = 0; i4 < MT; i4 += 4) {
        float4 ov;
        ov.x = xs[(i4 + 0) * 260 + tid];
        ov.y = xs[(i4 + 1) * 260 + tid];
        ov.z = xs[(i4 + 2) * 260 + tid];
        ov.w = xs[(i4 + 3) * 260 + tid];
        *(float4*)(on + i4) = ov;
    }
}

// ---------------------------------------------------------------------------
extern "C" void kernel_launch(void* const* d_in, const int* in_sizes, int n_in,
                              void* d_out, int out_size, void* d_ws, size_t ws_size,
                              hipStream_t stream) {
    const float* x        = (const float*)d_in[0];
    const float* conv1_w  = (const float*)d_in[1];
    const float* bn1_g    = (const float*)d_in[2];
    const float* bn1_b    = (const float*)d_in[3];
    const float* bn1_m    = (const float*)d_in[4];
    const float* bn1_v    = (const float*)d_in[5];
    const float* inproj_w = (const float*)d_in[6];
    const float* inproj_b = (const float*)d_in[7];
    const float* dw_w     = (const float*)d_in[8];
    const float* dw_b     = (const float*)d_in[9];
    const float* ln_g     = (const float*)d_in[10];
    const float* ln_b     = (const float*)d_in[11];
    const float* off_w    = (const float*)d_in[12];
    const float* off_b    = (const float*)d_in[13];
    const float* mask_w   = (const float*)d_in[14];
    const float* mask_b   = (const float*)d_in[15];
    const float* outproj_w = (const float*)d_in[16];
    const float* outproj_b = (const float*)d_in[17];
    const float* bn2_g    = (const float*)d_in[18];
    const float* bn2_b    = (const float*)d_in[19];
    const float* bn2_m    = (const float*)d_in[20];
    const float* bn2_v    = (const float*)d_in[21];
    float* out = (float*)d_out;

    // workspace layout
    short* Wc1b = (short*)d_ws;            // 65536 shorts
    short* Wipb = Wc1b + 65536;
    short* Whb  = Wipb + 65536;
    short* Wopb = Whb + 65536;
    float* fp   = (float*)(Wopb + 65536);
    float* bh   = fp;                      // 256
    float* sc1  = bh + 256;
    float* sh1  = sc1 + 256;
    float* sc2  = sh1 + 256;
    float* sh2  = sc2 + 256;
    float* y    = sh2 + 256;               // 2097152 (NHWC)
    float* xp   = y + 2097152;             // 2097152
    float* z    = xp + 2097152;            // 2097152
    float* offs = z + 2097152;             // 1179648
    float* msk  = offs + 1179648;          // 589824
    float* sbuf = z;                       // z dead after k_heads

    k_prep<<<dim3(CC), dim3(CC), 0, stream>>>(conv1_w, inproj_w, off_w, mask_w, outproj_w,
                                              off_b, mask_b, bn1_g, bn1_b, bn1_m, bn1_v,
                                              bn2_g, bn2_b, bn2_m, bn2_v,
                                              Wc1b, Wipb, Whb, Wopb, bh, sc1, sh1, sc2, sh2);
    k_conv_in<<<dim3(NPIX / MT), dim3(256), 0, stream>>>(x, Wc1b, Wipb, sc1, sh1, inproj_b, y, xp);
    k_dwln<<<dim3(NPIX / 4), dim3(256), 0, stream>>>(y, dw_w, dw_b, ln_g, ln_b, z);
    k_heads<<<dim3(NPIX / MT), dim3(256), 0, stream>>>(z, Whb, bh, offs, msk);
    k_dcn<<<dim3(NPIX / 4), dim3(256), 0, stream>>>(xp, offs, msk, sbuf);
    k_out<<<dim3(NPIX / MT), dim3(256), 0, stream>>>(sbuf, Wopb, outproj_b, sc2, sh2, out);
}